// Round 10
// baseline (326.340 us; speedup 1.0000x reference)
//
#include <hip/hip_runtime.h>
#include <cstdint>
#include <cstddef>

// N=100000, E=300000, B=50000, L=4, D_EMB=128, D_HID=64, H=8. fp32 in/out.
// R12: exp-hoist. node_agg's 8 __expf/edge were computed redundantly by all
// 64 lanes (512 lane-exps/edge). New k_exp pass (thread per slot*head,
// coalesced) converts logits -> softmax weights once and atomicAdds den.
// node_agg: ZERO transcendentals; per edge = 2 float4 loads + 4 gathers +
// 8 fma. scatter_logits also records dstc[pos]. Rest = R11 (Wcomb P-GEMM,
// atomicMax max-hoist, R7 scan shapes).
// Dispatches: 10 (memset, prep, dense(+hist), scan1, scan23, scatter_logits,
//                 exp, node_agg, gatefinal, output).

typedef __attribute__((ext_vector_type(8))) short bf16x8;
typedef __attribute__((ext_vector_type(4))) float f32x4;
typedef __attribute__((ext_vector_type(8))) unsigned short u16x8;

__device__ __forceinline__ unsigned short f2bf(float f) {
    unsigned u = __float_as_uint(f);
    unsigned r = u + 0x7fffu + ((u >> 16) & 1u);
    return (unsigned short)(r >> 16);
}
__device__ __forceinline__ float bf2f(unsigned short h) {
    return __uint_as_float((unsigned)h << 16);
}
// monotonic float<->unsigned order-preserving encode (for atomicMax)
__device__ __forceinline__ unsigned fenc(float f) {
    unsigned u = __float_as_uint(f);
    return (u & 0x80000000u) ? ~u : (u | 0x80000000u);
}
__device__ __forceinline__ float fdec(unsigned k) {
    unsigned u = (k & 0x80000000u) ? (k & 0x7fffffffu) : ~k;
    return __uint_as_float(u);
}

// ---------------------------------------------------------------------------
// Pack B = [Wi;Wp].T (K=128 x N=128) into MFMA B-frag order, split hi/lo bf16.
// Also pack Wcomb[128x16] (col i<8: Wi^T@attn_i; col 8+i: Wp^T@attn_i) as a
// single extra B-frag tile (Phi/Plo). Fused: batch-node multiplicity hist.
__global__ __launch_bounds__(256) void k_prep(
    const float* __restrict__ Wi, const float* __restrict__ Wp,
    const float* __restrict__ attn,
    unsigned short* __restrict__ Whi, unsigned short* __restrict__ Wlo,
    unsigned short* __restrict__ Phi, unsigned short* __restrict__ Plo,
    const int* __restrict__ batch_nodes, int* __restrict__ mult, int B) {
    int t = blockIdx.x * 256 + threadIdx.x;
    if (t < B) atomicAdd(&mult[batch_nodes[t]], 1);
    if (t < 16384) {
        int j = t & 7, L = (t >> 3) & 63, c = (t >> 9) & 7, s = t >> 12;
        int k = s * 32 + (L >> 4) * 8 + j;
        int n = c * 16 + (L & 15);
        float v = (n < 64) ? Wi[n * 128 + k] : Wp[(n - 64) * 128 + k];
        unsigned short h = f2bf(v);
        Whi[t] = h;
        Wlo[t] = f2bf(v - bf2f(h));
    } else if (t < 16384 + 2048) {
        int t2 = t - 16384;
        int j = t2 & 7, L = (t2 >> 3) & 63, s = t2 >> 9;
        int k = s * 32 + (L >> 4) * 8 + j;
        int i = L & 15;
        const float* Wsrc = (i < 8) ? Wi : Wp;
        const float* av = attn + (size_t)(i & 7) * 64;
        float v = 0.f;
#pragma unroll 8
        for (int d = 0; d < 64; ++d) v += av[d] * Wsrc[d * 128 + k];
        unsigned short h = f2bf(v);
        Phi[t2] = h;
        Plo[t2] = f2bf(v - bf2f(h));
    }
}

// ---------------------------------------------------------------------------
// Dense GEMM: Ybf[M x 128] = feat[M x 128] @ B, split-bf16 (3 MFMA per tile),
// plus P[M x 16] = feat @ Wcomb as a 9th col-tile. No LDS, no barriers, no
// cross-lane ops. P stored directly from accumulator (C/D layout).
__global__ __launch_bounds__(256, 4) void k_dense(
    const float* __restrict__ feat, const unsigned short* __restrict__ Whi,
    const unsigned short* __restrict__ Wlo, const unsigned short* __restrict__ Phi,
    const unsigned short* __restrict__ Plo,
    const int* __restrict__ edge_dst, const int* __restrict__ mult,
    int* __restrict__ count, unsigned short* __restrict__ Ybf,
    float* __restrict__ P, int M, int E) {
    int t = threadIdx.x;

    // edge-hist prologue (grid covers E: 1563 * 256 = 400k > 300k)
    {
        int e = blockIdx.x * 256 + t;
        if (e < E) {
            int d = edge_dst[e];
            if (mult[d] > 0) atomicAdd(&count[d], 1);
        }
    }

    int L = t & 63;
    int wave = t >> 6;
    int m = L & 15, q = L >> 4;
    int R0 = blockIdx.x * 64 + wave * 16;

    int rowc = R0 + m; if (rowc > M - 1) rowc = M - 1;
    const float* arow = feat + (size_t)rowc * 128;

    // hoist ALL A loads (8 x float4 = full 512B row slice for this lane)
    float4 av0[4], av1[4];
#pragma unroll
    for (int s = 0; s < 4; ++s) {
        const float4* ap = (const float4*)(arow + s * 32 + q * 8);
        av0[s] = ap[0];
        av1[s] = ap[1];
    }
    // convert all A to split hi/lo bf16 upfront
    bf16x8 ahi[4], alo[4];
#pragma unroll
    for (int s = 0; s < 4; ++s) {
        float av[8] = {av0[s].x, av0[s].y, av0[s].z, av0[s].w,
                       av1[s].x, av1[s].y, av1[s].z, av1[s].w};
#pragma unroll
        for (int j = 0; j < 8; ++j) {
            unsigned short h = f2bf(av[j]);
            ahi[s][j] = (short)h;
            alo[s][j] = (short)f2bf(av[j] - bf2f(h));
        }
    }

    f32x4 acc[8];
#pragma unroll
    for (int c = 0; c < 8; ++c) acc[c] = (f32x4){0.f, 0.f, 0.f, 0.f};
    f32x4 accP = (f32x4){0.f, 0.f, 0.f, 0.f};

    const bf16x8* gh = (const bf16x8*)Whi;
    const bf16x8* gl = (const bf16x8*)Wlo;
    const bf16x8* ph = (const bf16x8*)Phi;
    const bf16x8* pl = (const bf16x8*)Plo;
#pragma unroll
    for (int s = 0; s < 4; ++s) {
#pragma unroll
        for (int c = 0; c < 8; ++c) {
            bf16x8 bh = gh[(s * 8 + c) * 64 + L];
            bf16x8 bl = gl[(s * 8 + c) * 64 + L];
            acc[c] = __builtin_amdgcn_mfma_f32_16x16x32_bf16(ahi[s], bh, acc[c], 0, 0, 0);
            acc[c] = __builtin_amdgcn_mfma_f32_16x16x32_bf16(ahi[s], bl, acc[c], 0, 0, 0);
            acc[c] = __builtin_amdgcn_mfma_f32_16x16x32_bf16(alo[s], bh, acc[c], 0, 0, 0);
        }
        {
            bf16x8 bh = ph[s * 64 + L];
            bf16x8 bl = pl[s * 64 + L];
            accP = __builtin_amdgcn_mfma_f32_16x16x32_bf16(ahi[s], bh, accP, 0, 0, 0);
            accP = __builtin_amdgcn_mfma_f32_16x16x32_bf16(ahi[s], bl, accP, 0, 0, 0);
            accP = __builtin_amdgcn_mfma_f32_16x16x32_bf16(alo[s], bh, accP, 0, 0, 0);
        }
    }

    // C/D layout: col = lane&15 (=m), row = (lane>>4)*4 + reg (=q*4+r)
#pragma unroll
    for (int c = 0; c < 8; ++c) {
#pragma unroll
        for (int r = 0; r < 4; ++r) {
            int row = R0 + q * 4 + r;
            if (row < M) Ybf[(size_t)row * 128 + c * 16 + m] = f2bf(acc[c][r]);
        }
    }
    // P store: col i = m, rows q*4+r
#pragma unroll
    for (int r = 0; r < 4; ++r) {
        int row = R0 + q * 4 + r;
        if (row < M) P[(size_t)row * 16 + m] = accP[r];
    }
}

// ---------------------------------------------------------------------------
// per-block exclusive scan of count + block partial sums
__global__ __launch_bounds__(256) void k_scan1(
    const int* __restrict__ count, int* __restrict__ excl, int* __restrict__ partials, int N) {
    __shared__ int lds[256];
    int t = threadIdx.x, i = blockIdx.x * 256 + t;
    int c = (i < N) ? count[i] : 0;
    lds[t] = c; __syncthreads();
    for (int o = 1; o < 256; o <<= 1) {
        int v = (t >= o) ? lds[t - o] : 0;
        __syncthreads(); lds[t] += v; __syncthreads();
    }
    if (i < N) excl[i] = lds[t] - c;
    if (t == 255) partials[blockIdx.x] = lds[255];
}

// merged scan2+scan3
__global__ __launch_bounds__(256) void k_scan23(
    const int* __restrict__ excl, const int* __restrict__ partials,
    int* __restrict__ offsets, int* __restrict__ cursor, int N) {
    __shared__ int sacc[256];
    int bid = blockIdx.x, t = threadIdx.x;
    int s = 0;
    for (int j = t; j < bid; j += 256) s += partials[j];
    sacc[t] = s; __syncthreads();
#pragma unroll
    for (int o = 128; o > 0; o >>= 1) {
        if (t < o) sacc[t] += sacc[t + o];
        __syncthreads();
    }
    int boff = sacc[0];
    int i = bid * 256 + t;
    if (i < N) {
        int o = excl[i] + boff;
        offsets[i] = o; cursor[i] = o;
    }
    if (t == 0 && bid == gridDim.x - 1) offsets[N] = boff + partials[bid];
}

// ---------------------------------------------------------------------------
// Fused scatter + logits + per-(node,head) max (float-ordered atomicMax).
// 8 lanes per edge (h = lane&7). Also records dstc[pos] for k_exp.
__global__ __launch_bounds__(256) void k_scatter_logits(
    const int* __restrict__ edge_dst, const int* __restrict__ mult,
    int* __restrict__ cursor, const int* __restrict__ mp,
    const float* __restrict__ P, const float* __restrict__ Wth,
    float* __restrict__ logits, int4* __restrict__ mpc,
    unsigned* __restrict__ mxkey, int* __restrict__ dstc, int E) {
    int e = blockIdx.x * 32 + (threadIdx.x >> 3);
    if (e >= E) return;
    int h = threadIdx.x & 7;
    int d = edge_dst[e];
    if (mult[d] == 0) return;
    int pos = 0;
    if (h == 0) pos = atomicAdd(&cursor[d], 1);
    int gbase = threadIdx.x & ~7;
    pos = __shfl(pos, gbase);
    int4 rows = *(const int4*)(mp + (size_t)e * 4);
    float s = P[(size_t)rows.x * 16 + h] + P[(size_t)rows.w * 16 + h]
            + P[(size_t)rows.y * 16 + 8 + h] + P[(size_t)rows.z * 16 + 8 + h];
    float l = 0.f;
#pragma unroll
    for (int j = 0; j < 8; ++j) {
        float sj = __shfl(s, gbase + j);
        l += Wth[h * 8 + j] * sj;
    }
    l = l > 0.f ? l : 0.01f * l;
    logits[(size_t)pos * 8 + h] = l;
    atomicMax(&mxkey[(size_t)d * 8 + h], fenc(l));
    if (h == 0) { mpc[pos] = rows; dstc[pos] = d; }
}

// ---------------------------------------------------------------------------
// Per (slot, head): logits -> exp(l - mx) in place; accumulate den per
// (node, head). Coalesced; one exp per value chip-wide (not 64x redundant).
__global__ __launch_bounds__(256) void k_exp(
    const int* __restrict__ pEc, const int* __restrict__ dstc,
    const unsigned* __restrict__ mxkey, float* __restrict__ logits,
    float* __restrict__ den) {
    int idx = blockIdx.x * 256 + threadIdx.x;
    int Ec = *pEc;
    int j = idx >> 3;
    if (j >= Ec) return;
    int h = idx & 7;
    int d = dstc[j];
    float mx = fdec(mxkey[(size_t)d * 8 + h]);
    float wv = __expf(logits[idx] - mx);
    logits[idx] = wv;
    atomicAdd(&den[(size_t)d * 8 + h], wv);
}

// ---------------------------------------------------------------------------
// Per flagged node: weighted aggregation from Ybf. Weights precomputed by
// k_exp (logits holds w; den holds denominators). ZERO transcendentals.
__global__ __launch_bounds__(256) void k_node_agg(
    const unsigned short* __restrict__ Ybf, const float* __restrict__ logits,
    const int4* __restrict__ mpc, const int* __restrict__ offsets,
    const int* __restrict__ mult, const float* __restrict__ den,
    const float* __restrict__ Wg,
    unsigned short* __restrict__ nftb, float* __restrict__ gate_part, int N) {
    int n = blockIdx.x * 4 + (threadIdx.x >> 6);
    int lane = threadIdx.x & 63;
    if (n >= N) return;
    int m = mult[n];
    if (m == 0) return;
    int beg = offsets[n], end = offsets[n + 1];

    float acc[8];
#pragma unroll
    for (int h = 0; h < 8; ++h) acc[h] = 0.f;

    for (int j = beg; j < end; ++j) {
        const float4* lp = (const float4*)(logits + (size_t)j * 8);
        float4 w0 = lp[0], w1 = lp[1];
        int4 rows = mpc[j];
        float ed = bf2f(Ybf[(size_t)rows.x * 128 + lane])
                 + bf2f(Ybf[(size_t)rows.w * 128 + lane])
                 + bf2f(Ybf[(size_t)rows.y * 128 + 64 + lane])
                 + bf2f(Ybf[(size_t)rows.z * 128 + 64 + lane]);
        acc[0] += w0.x * ed; acc[1] += w0.y * ed;
        acc[2] += w0.z * ed; acc[3] += w0.w * ed;
        acc[4] += w1.x * ed; acc[5] += w1.y * ed;
        acc[6] += w1.z * ed; acc[7] += w1.w * ed;
    }

#pragma unroll
    for (int h = 0; h < 8; ++h) {
        float dh = den[(size_t)n * 8 + h];
        float r = (end > beg) ? 1.f / dh : 0.f;
        acc[h] *= r;
    }

    unsigned short* base = nftb + (size_t)n * 512;
#pragma unroll
    for (int h = 0; h < 8; ++h) base[h * 64 + lane] = f2bf(acc[h]);

    float wg = Wg[lane];
    float myg = 0.f;
#pragma unroll
    for (int h = 0; h < 8; ++h) {
        float p = acc[h] * wg;
#pragma unroll
        for (int o = 32; o > 0; o >>= 1) p += __shfl_xor(p, o);
        if (lane == h) myg = p;
    }
    if (lane < 8)
        atomicAdd(&gate_part[(blockIdx.x & 1023) * 8 + lane], (float)m * myg);
}

// gate[h] = sum(gate_part)/B + b_gate
__global__ __launch_bounds__(256) void k_gatefinal(
    const float* __restrict__ gate_part, const float* __restrict__ b_gate,
    float* __restrict__ gate, int B) {
    __shared__ float lds[256];
    int t = threadIdx.x;
    int h = t & 7, g = t >> 3;
    float s = 0.f;
    for (int b = g; b < 1024; b += 32) s += gate_part[b * 8 + h];
    lds[t] = s; __syncthreads();
    if (t < 8) {
        float tot = 0.f;
        for (int gg = 0; gg < 32; ++gg) tot += lds[gg * 8 + t];
        gate[t] = tot / (float)B + b_gate[0];
    }
}

// out[b, h*64+d] = nftb[batch_nodes[b]] * gate[h]  -- 16B/lane, NT stores
__global__ __launch_bounds__(256) void k_output(
    const unsigned short* __restrict__ nftb, const int* __restrict__ batch_nodes,
    const float* __restrict__ gate, float* __restrict__ out, int B) {
    int idx = blockIdx.x * 256 + threadIdx.x;
    int total = B * 64;
    if (idx >= total) return;
    int b = idx >> 6;
    int r = idx & 63;
    int h = r >> 3;
    int n = batch_nodes[b];
    u16x8 v = *(const u16x8*)(nftb + (size_t)n * 512 + r * 8);
    float g = gate[h];
    f32x4 o0, o1;
    o0[0] = bf2f(v[0]) * g; o0[1] = bf2f(v[1]) * g;
    o0[2] = bf2f(v[2]) * g; o0[3] = bf2f(v[3]) * g;
    o1[0] = bf2f(v[4]) * g; o1[1] = bf2f(v[5]) * g;
    o1[2] = bf2f(v[6]) * g; o1[3] = bf2f(v[7]) * g;
    f32x4* op = (f32x4*)(out + (size_t)idx * 8);
    __builtin_nontemporal_store(o0, op);
    __builtin_nontemporal_store(o1, op + 1);
}

// ---------------------------------------------------------------------------
extern "C" void kernel_launch(void* const* d_in, const int* in_sizes, int n_in,
                              void* d_out, int out_size, void* d_ws, size_t ws_size,
                              hipStream_t stream) {
    const int*   batch_nodes = (const int*)d_in[0];
    const int*   mp          = (const int*)d_in[1];
    const int*   edge_dst    = (const int*)d_in[2];
    const float* feat        = (const float*)d_in[3];
    const float* W_i         = (const float*)d_in[4];
    const float* W_p         = (const float*)d_in[5];
    const float* attn        = (const float*)d_in[6];
    const float* W_th        = (const float*)d_in[7];
    const float* W_gate      = (const float*)d_in[8];
    const float* b_gate      = (const float*)d_in[9];
    float* out = (float*)d_out;

    const int B = in_sizes[0];
    const int E = in_sizes[2];
    const int N = in_sizes[3] / 128;
    const int nb_scan = (N + 255) / 256;

    char* w = (char*)d_ws;
    auto alloc = [&](size_t bytes) -> void* {
        void* p = (void*)w;
        w += (bytes + 255) & ~(size_t)255;
        return p;
    };
    unsigned short* Whi = (unsigned short*)alloc(16384 * 2);
    unsigned short* Wlo = (unsigned short*)alloc(16384 * 2);
    unsigned short* Phi = (unsigned short*)alloc(2048 * 2);
    unsigned short* Plo = (unsigned short*)alloc(2048 * 2);
    unsigned short* Ybf = (unsigned short*)alloc((size_t)N * 128 * 2);   // 25.6 MB
    float* P            = (float*)alloc((size_t)N * 16 * 4);             // 6.4 MB
    float* logits       = (float*)alloc((size_t)E * 8 * 4);              // 9.6 MB
    int4*  mpc          = (int4*)alloc((size_t)E * 16);                  // 4.8 MB
    int*   dstc         = (int*)alloc((size_t)E * 4);                    // 1.2 MB
    // contiguous zero region: mult | count | gate_part | mxkey | den
    size_t zero_bytes   = (size_t)N * 4 + (size_t)N * 4 + 1024 * 8 * 4
                        + (size_t)N * 8 * 4 + (size_t)N * 8 * 4;
    int*   mult         = (int*)alloc(zero_bytes);
    int*   count        = mult + N;
    float* gate_part    = (float*)(count + N);
    unsigned* mxkey     = (unsigned*)(gate_part + 8192);
    float* den          = (float*)(mxkey + (size_t)N * 8);
    int*   excl         = (int*)alloc((size_t)N * 4);
    int*   offsets      = (int*)alloc((size_t)(N + 1) * 4);
    int*   cursor       = (int*)alloc((size_t)N * 4);
    int*   partials     = (int*)alloc(512 * 4);
    unsigned short* nftb = (unsigned short*)alloc((size_t)N * 512 * 2);  // 102.4 MB
    float* gate         = (float*)alloc(256);

    hipMemsetAsync(mult, 0, zero_bytes, stream);

    int prep_work = (B > 16384 + 2048) ? B : 16384 + 2048;
    k_prep<<<(prep_work + 255) / 256, 256, 0, stream>>>(W_i, W_p, attn,
                                                        Whi, Wlo, Phi, Plo,
                                                        batch_nodes, mult, B);
    k_dense<<<(N + 63) / 64, 256, 0, stream>>>(feat, Whi, Wlo, Phi, Plo,
                                               edge_dst, mult, count, Ybf, P, N, E);
    k_scan1<<<nb_scan, 256, 0, stream>>>(count, excl, partials, N);
    k_scan23<<<nb_scan, 256, 0, stream>>>(excl, partials, offsets, cursor, N);
    k_scatter_logits<<<(E + 31) / 32, 256, 0, stream>>>(edge_dst, mult, cursor,
                                                        mp, P, W_th, logits, mpc,
                                                        mxkey, dstc, E);
    const int* pEc = offsets + N;
    k_exp<<<(E * 8 + 255) / 256, 256, 0, stream>>>(pEc, dstc, mxkey, logits, den);
    k_node_agg<<<(N + 3) / 4, 256, 0, stream>>>(Ybf, logits, mpc, offsets, mult,
                                                den, W_gate, nftb, gate_part, N);
    k_gatefinal<<<1, 256, 0, stream>>>(gate_part, b_gate, gate, B);
    k_output<<<(B * 64 + 255) / 256, 256, 0, stream>>>(nftb, batch_nodes, gate, out, B);
}

// Round 11
// 317.979 us; speedup vs baseline: 1.0263x; 1.0263x over previous
//
#include <hip/hip_runtime.h>
#include <cstdint>
#include <cstddef>

// N=100000, E=300000, B=50000, L=4, D_EMB=128, D_HID=64, H=8. fp32 in/out.
// R13: revert R12 (exp-hoist regressed: node_agg is gather-bound, not
// VALU-bound) back to R11 base; k_dense now 32 rows/wave with B-register
// reuse: each (s,c) B-frag pair loaded once feeds 6 MFMAs (2 row-sets).
// Per-wave B L2 traffic halves (800->400 MB chip-wide). launch_bounds(256,3)
// for ~170 VGPR (state: 64 A + 64 acc + 8 accP). Grid halves to 782;
// edge-hist prologue grid-strided. Rest identical to R11 (Wcomb P-GEMM,
// atomicMax max-hoist, plain-softmax node_agg, R7 scan shapes).
// Dispatches: 9 (memset, prep, dense(+hist), scan1, scan23, scatter_logits,
//                node_agg, gatefinal, output).

typedef __attribute__((ext_vector_type(8))) short bf16x8;
typedef __attribute__((ext_vector_type(4))) float f32x4;
typedef __attribute__((ext_vector_type(8))) unsigned short u16x8;

__device__ __forceinline__ unsigned short f2bf(float f) {
    unsigned u = __float_as_uint(f);
    unsigned r = u + 0x7fffu + ((u >> 16) & 1u);
    return (unsigned short)(r >> 16);
}
__device__ __forceinline__ float bf2f(unsigned short h) {
    return __uint_as_float((unsigned)h << 16);
}
// monotonic float<->unsigned order-preserving encode (for atomicMax)
__device__ __forceinline__ unsigned fenc(float f) {
    unsigned u = __float_as_uint(f);
    return (u & 0x80000000u) ? ~u : (u | 0x80000000u);
}
__device__ __forceinline__ float fdec(unsigned k) {
    unsigned u = (k & 0x80000000u) ? (k & 0x7fffffffu) : ~k;
    return __uint_as_float(u);
}

// ---------------------------------------------------------------------------
// Pack B = [Wi;Wp].T (K=128 x N=128) into MFMA B-frag order, split hi/lo bf16.
// Also pack Wcomb[128x16] (col i<8: Wi^T@attn_i; col 8+i: Wp^T@attn_i) as a
// single extra B-frag tile (Phi/Plo). Fused: batch-node multiplicity hist.
__global__ __launch_bounds__(256) void k_prep(
    const float* __restrict__ Wi, const float* __restrict__ Wp,
    const float* __restrict__ attn,
    unsigned short* __restrict__ Whi, unsigned short* __restrict__ Wlo,
    unsigned short* __restrict__ Phi, unsigned short* __restrict__ Plo,
    const int* __restrict__ batch_nodes, int* __restrict__ mult, int B) {
    int t = blockIdx.x * 256 + threadIdx.x;
    if (t < B) atomicAdd(&mult[batch_nodes[t]], 1);
    if (t < 16384) {
        int j = t & 7, L = (t >> 3) & 63, c = (t >> 9) & 7, s = t >> 12;
        int k = s * 32 + (L >> 4) * 8 + j;
        int n = c * 16 + (L & 15);
        float v = (n < 64) ? Wi[n * 128 + k] : Wp[(n - 64) * 128 + k];
        unsigned short h = f2bf(v);
        Whi[t] = h;
        Wlo[t] = f2bf(v - bf2f(h));
    } else if (t < 16384 + 2048) {
        int t2 = t - 16384;
        int j = t2 & 7, L = (t2 >> 3) & 63, s = t2 >> 9;
        int k = s * 32 + (L >> 4) * 8 + j;
        int i = L & 15;
        const float* Wsrc = (i < 8) ? Wi : Wp;
        const float* av = attn + (size_t)(i & 7) * 64;
        float v = 0.f;
#pragma unroll 8
        for (int d = 0; d < 64; ++d) v += av[d] * Wsrc[d * 128 + k];
        unsigned short h = f2bf(v);
        Phi[t2] = h;
        Plo[t2] = f2bf(v - bf2f(h));
    }
}

// ---------------------------------------------------------------------------
// Dense GEMM: Ybf[M x 128] = feat[M x 128] @ B, split-bf16, plus
// P[M x 16] = feat @ Wcomb. 32 rows/wave (2 row-sets): each B-frag pair
// (bh,bl) loaded once from L2 feeds 6 MFMAs. No LDS, no barriers, no
// cross-lane ops. Grid = (M+127)/128; hist prologue grid-strided.
__global__ __launch_bounds__(256, 3) void k_dense(
    const float* __restrict__ feat, const unsigned short* __restrict__ Whi,
    const unsigned short* __restrict__ Wlo, const unsigned short* __restrict__ Phi,
    const unsigned short* __restrict__ Plo,
    const int* __restrict__ edge_dst, const int* __restrict__ mult,
    int* __restrict__ count, unsigned short* __restrict__ Ybf,
    float* __restrict__ P, int M, int E) {
    int t = threadIdx.x;

    // edge-hist prologue, grid-strided (782*256 = 200k threads, E = 300k)
    {
        int nth = gridDim.x * 256;
        for (int e = blockIdx.x * 256 + t; e < E; e += nth) {
            int d = edge_dst[e];
            if (mult[d] > 0) atomicAdd(&count[d], 1);
        }
    }

    int L = t & 63;
    int wave = t >> 6;
    int m = L & 15, q = L >> 4;
    int Rbase = blockIdx.x * 128 + wave * 16;   // row-set rs at Rbase + rs*64

    // load + convert A for both row-sets
    bf16x8 ahi[2][4], alo[2][4];
#pragma unroll
    for (int rs = 0; rs < 2; ++rs) {
        int R0 = Rbase + rs * 64;
        int rowc = R0 + m; if (rowc > M - 1) rowc = M - 1;
        const float* arow = feat + (size_t)rowc * 128;
#pragma unroll
        for (int s = 0; s < 4; ++s) {
            const float4* ap = (const float4*)(arow + s * 32 + q * 8);
            float4 a0 = ap[0], a1 = ap[1];
            float av[8] = {a0.x, a0.y, a0.z, a0.w, a1.x, a1.y, a1.z, a1.w};
#pragma unroll
            for (int j = 0; j < 8; ++j) {
                unsigned short h = f2bf(av[j]);
                ahi[rs][s][j] = (short)h;
                alo[rs][s][j] = (short)f2bf(av[j] - bf2f(h));
            }
        }
    }

    f32x4 acc[2][8];
    f32x4 accP[2];
#pragma unroll
    for (int rs = 0; rs < 2; ++rs) {
#pragma unroll
        for (int c = 0; c < 8; ++c) acc[rs][c] = (f32x4){0.f, 0.f, 0.f, 0.f};
        accP[rs] = (f32x4){0.f, 0.f, 0.f, 0.f};
    }

    const bf16x8* gh = (const bf16x8*)Whi;
    const bf16x8* gl = (const bf16x8*)Wlo;
    const bf16x8* ph = (const bf16x8*)Phi;
    const bf16x8* pl = (const bf16x8*)Plo;
#pragma unroll
    for (int s = 0; s < 4; ++s) {
#pragma unroll
        for (int c = 0; c < 8; ++c) {
            bf16x8 bh = gh[(s * 8 + c) * 64 + L];
            bf16x8 bl = gl[(s * 8 + c) * 64 + L];
            acc[0][c] = __builtin_amdgcn_mfma_f32_16x16x32_bf16(ahi[0][s], bh, acc[0][c], 0, 0, 0);
            acc[0][c] = __builtin_amdgcn_mfma_f32_16x16x32_bf16(ahi[0][s], bl, acc[0][c], 0, 0, 0);
            acc[0][c] = __builtin_amdgcn_mfma_f32_16x16x32_bf16(alo[0][s], bh, acc[0][c], 0, 0, 0);
            acc[1][c] = __builtin_amdgcn_mfma_f32_16x16x32_bf16(ahi[1][s], bh, acc[1][c], 0, 0, 0);
            acc[1][c] = __builtin_amdgcn_mfma_f32_16x16x32_bf16(ahi[1][s], bl, acc[1][c], 0, 0, 0);
            acc[1][c] = __builtin_amdgcn_mfma_f32_16x16x32_bf16(alo[1][s], bh, acc[1][c], 0, 0, 0);
        }
        {
            bf16x8 bh = ph[s * 64 + L];
            bf16x8 bl = pl[s * 64 + L];
            accP[0] = __builtin_amdgcn_mfma_f32_16x16x32_bf16(ahi[0][s], bh, accP[0], 0, 0, 0);
            accP[0] = __builtin_amdgcn_mfma_f32_16x16x32_bf16(ahi[0][s], bl, accP[0], 0, 0, 0);
            accP[0] = __builtin_amdgcn_mfma_f32_16x16x32_bf16(alo[0][s], bh, accP[0], 0, 0, 0);
            accP[1] = __builtin_amdgcn_mfma_f32_16x16x32_bf16(ahi[1][s], bh, accP[1], 0, 0, 0);
            accP[1] = __builtin_amdgcn_mfma_f32_16x16x32_bf16(ahi[1][s], bl, accP[1], 0, 0, 0);
            accP[1] = __builtin_amdgcn_mfma_f32_16x16x32_bf16(alo[1][s], bh, accP[1], 0, 0, 0);
        }
    }

    // C/D layout: col = lane&15 (=m), row = (lane>>4)*4 + reg (=q*4+r)
#pragma unroll
    for (int rs = 0; rs < 2; ++rs) {
        int R0 = Rbase + rs * 64;
#pragma unroll
        for (int c = 0; c < 8; ++c) {
#pragma unroll
            for (int r = 0; r < 4; ++r) {
                int row = R0 + q * 4 + r;
                if (row < M) Ybf[(size_t)row * 128 + c * 16 + m] = f2bf(acc[rs][c][r]);
            }
        }
#pragma unroll
        for (int r = 0; r < 4; ++r) {
            int row = R0 + q * 4 + r;
            if (row < M) P[(size_t)row * 16 + m] = accP[rs][r];
        }
    }
}

// ---------------------------------------------------------------------------
// per-block exclusive scan of count + block partial sums
__global__ __launch_bounds__(256) void k_scan1(
    const int* __restrict__ count, int* __restrict__ excl, int* __restrict__ partials, int N) {
    __shared__ int lds[256];
    int t = threadIdx.x, i = blockIdx.x * 256 + t;
    int c = (i < N) ? count[i] : 0;
    lds[t] = c; __syncthreads();
    for (int o = 1; o < 256; o <<= 1) {
        int v = (t >= o) ? lds[t - o] : 0;
        __syncthreads(); lds[t] += v; __syncthreads();
    }
    if (i < N) excl[i] = lds[t] - c;
    if (t == 255) partials[blockIdx.x] = lds[255];
}

// merged scan2+scan3
__global__ __launch_bounds__(256) void k_scan23(
    const int* __restrict__ excl, const int* __restrict__ partials,
    int* __restrict__ offsets, int* __restrict__ cursor, int N) {
    __shared__ int sacc[256];
    int bid = blockIdx.x, t = threadIdx.x;
    int s = 0;
    for (int j = t; j < bid; j += 256) s += partials[j];
    sacc[t] = s; __syncthreads();
#pragma unroll
    for (int o = 128; o > 0; o >>= 1) {
        if (t < o) sacc[t] += sacc[t + o];
        __syncthreads();
    }
    int boff = sacc[0];
    int i = bid * 256 + t;
    if (i < N) {
        int o = excl[i] + boff;
        offsets[i] = o; cursor[i] = o;
    }
    if (t == 0 && bid == gridDim.x - 1) offsets[N] = boff + partials[bid];
}

// ---------------------------------------------------------------------------
// Fused scatter + logits + per-(node,head) max (float-ordered atomicMax).
// 8 lanes per edge (h = lane&7).
__global__ __launch_bounds__(256) void k_scatter_logits(
    const int* __restrict__ edge_dst, const int* __restrict__ mult,
    int* __restrict__ cursor, const int* __restrict__ mp,
    const float* __restrict__ P, const float* __restrict__ Wth,
    float* __restrict__ logits, int4* __restrict__ mpc,
    unsigned* __restrict__ mxkey, int E) {
    int e = blockIdx.x * 32 + (threadIdx.x >> 3);
    if (e >= E) return;
    int h = threadIdx.x & 7;
    int d = edge_dst[e];
    if (mult[d] == 0) return;
    int pos = 0;
    if (h == 0) pos = atomicAdd(&cursor[d], 1);
    int gbase = threadIdx.x & ~7;
    pos = __shfl(pos, gbase);
    int4 rows = *(const int4*)(mp + (size_t)e * 4);
    float s = P[(size_t)rows.x * 16 + h] + P[(size_t)rows.w * 16 + h]
            + P[(size_t)rows.y * 16 + 8 + h] + P[(size_t)rows.z * 16 + 8 + h];
    float l = 0.f;
#pragma unroll
    for (int j = 0; j < 8; ++j) {
        float sj = __shfl(s, gbase + j);
        l += Wth[h * 8 + j] * sj;
    }
    l = l > 0.f ? l : 0.01f * l;
    logits[(size_t)pos * 8 + h] = l;
    atomicMax(&mxkey[(size_t)d * 8 + h], fenc(l));
    if (h == 0) mpc[pos] = rows;
}

// ---------------------------------------------------------------------------
// Per flagged node: single-pass plain softmax (max precomputed in mxkey) +
// aggregation from Ybf. One wave per node, lane = d. 8 exps/edge.
__global__ __launch_bounds__(256) void k_node_agg(
    const unsigned short* __restrict__ Ybf, const float* __restrict__ logits,
    const int4* __restrict__ mpc, const int* __restrict__ offsets,
    const int* __restrict__ mult, const unsigned* __restrict__ mxkey,
    const float* __restrict__ Wg,
    unsigned short* __restrict__ nftb, float* __restrict__ gate_part, int N) {
    int n = blockIdx.x * 4 + (threadIdx.x >> 6);
    int lane = threadIdx.x & 63;
    if (n >= N) return;
    int m = mult[n];
    if (m == 0) return;
    int beg = offsets[n], end = offsets[n + 1];

    float mx[8], den[8], acc[8];
#pragma unroll
    for (int h = 0; h < 8; ++h) {
        mx[h] = fdec(mxkey[(size_t)n * 8 + h]);
        den[h] = 0.f; acc[h] = 0.f;
    }

    for (int j = beg; j < end; ++j) {
        const float4* lp = (const float4*)(logits + (size_t)j * 8);
        float4 l0 = lp[0], l1 = lp[1];
        int4 rows = mpc[j];
        float ed = bf2f(Ybf[(size_t)rows.x * 128 + lane])
                 + bf2f(Ybf[(size_t)rows.w * 128 + lane])
                 + bf2f(Ybf[(size_t)rows.y * 128 + 64 + lane])
                 + bf2f(Ybf[(size_t)rows.z * 128 + 64 + lane]);
        float w0 = __expf(l0.x - mx[0]), w1 = __expf(l0.y - mx[1]);
        float w2 = __expf(l0.z - mx[2]), w3 = __expf(l0.w - mx[3]);
        float w4 = __expf(l1.x - mx[4]), w5 = __expf(l1.y - mx[5]);
        float w6 = __expf(l1.z - mx[6]), w7 = __expf(l1.w - mx[7]);
        den[0] += w0; den[1] += w1; den[2] += w2; den[3] += w3;
        den[4] += w4; den[5] += w5; den[6] += w6; den[7] += w7;
        acc[0] += w0 * ed; acc[1] += w1 * ed; acc[2] += w2 * ed; acc[3] += w3 * ed;
        acc[4] += w4 * ed; acc[5] += w5 * ed; acc[6] += w6 * ed; acc[7] += w7 * ed;
    }

#pragma unroll
    for (int h = 0; h < 8; ++h) {
        float r = (end > beg) ? 1.f / den[h] : 0.f;
        acc[h] *= r;
    }

    unsigned short* base = nftb + (size_t)n * 512;
#pragma unroll
    for (int h = 0; h < 8; ++h) base[h * 64 + lane] = f2bf(acc[h]);

    float wg = Wg[lane];
    float myg = 0.f;
#pragma unroll
    for (int h = 0; h < 8; ++h) {
        float p = acc[h] * wg;
#pragma unroll
        for (int o = 32; o > 0; o >>= 1) p += __shfl_xor(p, o);
        if (lane == h) myg = p;
    }
    if (lane < 8)
        atomicAdd(&gate_part[(blockIdx.x & 1023) * 8 + lane], (float)m * myg);
}

// gate[h] = sum(gate_part)/B + b_gate
__global__ __launch_bounds__(256) void k_gatefinal(
    const float* __restrict__ gate_part, const float* __restrict__ b_gate,
    float* __restrict__ gate, int B) {
    __shared__ float lds[256];
    int t = threadIdx.x;
    int h = t & 7, g = t >> 3;
    float s = 0.f;
    for (int b = g; b < 1024; b += 32) s += gate_part[b * 8 + h];
    lds[t] = s; __syncthreads();
    if (t < 8) {
        float tot = 0.f;
        for (int gg = 0; gg < 32; ++gg) tot += lds[gg * 8 + t];
        gate[t] = tot / (float)B + b_gate[0];
    }
}

// out[b, h*64+d] = nftb[batch_nodes[b]] * gate[h]  -- 16B/lane, NT stores
__global__ __launch_bounds__(256) void k_output(
    const unsigned short* __restrict__ nftb, const int* __restrict__ batch_nodes,
    const float* __restrict__ gate, float* __restrict__ out, int B) {
    int idx = blockIdx.x * 256 + threadIdx.x;
    int total = B * 64;
    if (idx >= total) return;
    int b = idx >> 6;
    int r = idx & 63;
    int h = r >> 3;
    int n = batch_nodes[b];
    u16x8 v = *(const u16x8*)(nftb + (size_t)n * 512 + r * 8);
    float g = gate[h];
    f32x4 o0, o1;
    o0[0] = bf2f(v[0]) * g; o0[1] = bf2f(v[1]) * g;
    o0[2] = bf2f(v[2]) * g; o0[3] = bf2f(v[3]) * g;
    o1[0] = bf2f(v[4]) * g; o1[1] = bf2f(v[5]) * g;
    o1[2] = bf2f(v[6]) * g; o1[3] = bf2f(v[7]) * g;
    f32x4* op = (f32x4*)(out + (size_t)idx * 8);
    __builtin_nontemporal_store(o0, op);
    __builtin_nontemporal_store(o1, op + 1);
}

// ---------------------------------------------------------------------------
extern "C" void kernel_launch(void* const* d_in, const int* in_sizes, int n_in,
                              void* d_out, int out_size, void* d_ws, size_t ws_size,
                              hipStream_t stream) {
    const int*   batch_nodes = (const int*)d_in[0];
    const int*   mp          = (const int*)d_in[1];
    const int*   edge_dst    = (const int*)d_in[2];
    const float* feat        = (const float*)d_in[3];
    const float* W_i         = (const float*)d_in[4];
    const float* W_p         = (const float*)d_in[5];
    const float* attn        = (const float*)d_in[6];
    const float* W_th        = (const float*)d_in[7];
    const float* W_gate      = (const float*)d_in[8];
    const float* b_gate      = (const float*)d_in[9];
    float* out = (float*)d_out;

    const int B = in_sizes[0];
    const int E = in_sizes[2];
    const int N = in_sizes[3] / 128;
    const int nb_scan = (N + 255) / 256;

    char* w = (char*)d_ws;
    auto alloc = [&](size_t bytes) -> void* {
        void* p = (void*)w;
        w += (bytes + 255) & ~(size_t)255;
        return p;
    };
    unsigned short* Whi = (unsigned short*)alloc(16384 * 2);
    unsigned short* Wlo = (unsigned short*)alloc(16384 * 2);
    unsigned short* Phi = (unsigned short*)alloc(2048 * 2);
    unsigned short* Plo = (unsigned short*)alloc(2048 * 2);
    unsigned short* Ybf = (unsigned short*)alloc((size_t)N * 128 * 2);   // 25.6 MB
    float* P            = (float*)alloc((size_t)N * 16 * 4);             // 6.4 MB
    float* logits       = (float*)alloc((size_t)E * 8 * 4);              // 9.6 MB
    int4*  mpc          = (int4*)alloc((size_t)E * 16);                  // 4.8 MB
    // contiguous zero region: mult | count | gate_part | mxkey (single memset)
    size_t zero_bytes   = (size_t)N * 4 + (size_t)N * 4 + 1024 * 8 * 4
                        + (size_t)N * 8 * 4;
    int*   mult         = (int*)alloc(zero_bytes);
    int*   count        = mult + N;
    float* gate_part    = (float*)(count + N);
    unsigned* mxkey     = (unsigned*)(gate_part + 8192);
    int*   excl         = (int*)alloc((size_t)N * 4);
    int*   offsets      = (int*)alloc((size_t)(N + 1) * 4);
    int*   cursor       = (int*)alloc((size_t)N * 4);
    int*   partials     = (int*)alloc(512 * 4);
    unsigned short* nftb = (unsigned short*)alloc((size_t)N * 512 * 2);  // 102.4 MB
    float* gate         = (float*)alloc(256);

    hipMemsetAsync(mult, 0, zero_bytes, stream);

    int prep_work = (B > 16384 + 2048) ? B : 16384 + 2048;
    k_prep<<<(prep_work + 255) / 256, 256, 0, stream>>>(W_i, W_p, attn,
                                                        Whi, Wlo, Phi, Plo,
                                                        batch_nodes, mult, B);
    k_dense<<<(N + 127) / 128, 256, 0, stream>>>(feat, Whi, Wlo, Phi, Plo,
                                                 edge_dst, mult, count, Ybf, P, N, E);
    k_scan1<<<nb_scan, 256, 0, stream>>>(count, excl, partials, N);
    k_scan23<<<nb_scan, 256, 0, stream>>>(excl, partials, offsets, cursor, N);
    k_scatter_logits<<<(E + 31) / 32, 256, 0, stream>>>(edge_dst, mult, cursor,
                                                        mp, P, W_th, logits, mpc,
                                                        mxkey, E);
    k_node_agg<<<(N + 3) / 4, 256, 0, stream>>>(Ybf, logits, mpc, offsets, mult,
                                                mxkey, W_gate, nftb, gate_part, N);
    k_gatefinal<<<1, 256, 0, stream>>>(gate_part, b_gate, gate, B);
    k_output<<<(B * 64 + 255) / 256, 256, 0, stream>>>(nftb, batch_nodes, gate, out, B);
}

// Round 12
// 313.506 us; speedup vs baseline: 1.0409x; 1.0143x over previous
//
#include <hip/hip_runtime.h>
#include <cstdint>
#include <cstddef>

// N=100000, E=300000, B=50000, L=4, D_EMB=128, D_HID=64, H=8. fp32 in/out.
// R14: revert R13 (2-row k_dense spilled: VGPR=84 vs 136 live, scratch)
// to R11's k_dense. Changes vs R11:
//  (1) node_agg: block = 2 nodes x 2 waves; alternating edges per wave,
//      partials combined via LDS -> serial gather chain per node halves.
//  (2) gatefinal folded into k_output (isolated this time); gate_part
//      shrunk to 256 slots so per-block redundant reduce is ~8KB.
// Dispatches: 8 (memset, prep, dense(+hist), scan1, scan23, scatter_logits,
//                node_agg, output(+gate)).

typedef __attribute__((ext_vector_type(8))) short bf16x8;
typedef __attribute__((ext_vector_type(4))) float f32x4;
typedef __attribute__((ext_vector_type(8))) unsigned short u16x8;

__device__ __forceinline__ unsigned short f2bf(float f) {
    unsigned u = __float_as_uint(f);
    unsigned r = u + 0x7fffu + ((u >> 16) & 1u);
    return (unsigned short)(r >> 16);
}
__device__ __forceinline__ float bf2f(unsigned short h) {
    return __uint_as_float((unsigned)h << 16);
}
// monotonic float<->unsigned order-preserving encode (for atomicMax)
__device__ __forceinline__ unsigned fenc(float f) {
    unsigned u = __float_as_uint(f);
    return (u & 0x80000000u) ? ~u : (u | 0x80000000u);
}
__device__ __forceinline__ float fdec(unsigned k) {
    unsigned u = (k & 0x80000000u) ? (k & 0x7fffffffu) : ~k;
    return __uint_as_float(u);
}

// ---------------------------------------------------------------------------
// Pack B = [Wi;Wp].T (K=128 x N=128) into MFMA B-frag order, split hi/lo bf16.
// Also pack Wcomb[128x16] (col i<8: Wi^T@attn_i; col 8+i: Wp^T@attn_i) as a
// single extra B-frag tile (Phi/Plo). Fused: batch-node multiplicity hist.
__global__ __launch_bounds__(256) void k_prep(
    const float* __restrict__ Wi, const float* __restrict__ Wp,
    const float* __restrict__ attn,
    unsigned short* __restrict__ Whi, unsigned short* __restrict__ Wlo,
    unsigned short* __restrict__ Phi, unsigned short* __restrict__ Plo,
    const int* __restrict__ batch_nodes, int* __restrict__ mult, int B) {
    int t = blockIdx.x * 256 + threadIdx.x;
    if (t < B) atomicAdd(&mult[batch_nodes[t]], 1);
    if (t < 16384) {
        int j = t & 7, L = (t >> 3) & 63, c = (t >> 9) & 7, s = t >> 12;
        int k = s * 32 + (L >> 4) * 8 + j;
        int n = c * 16 + (L & 15);
        float v = (n < 64) ? Wi[n * 128 + k] : Wp[(n - 64) * 128 + k];
        unsigned short h = f2bf(v);
        Whi[t] = h;
        Wlo[t] = f2bf(v - bf2f(h));
    } else if (t < 16384 + 2048) {
        int t2 = t - 16384;
        int j = t2 & 7, L = (t2 >> 3) & 63, s = t2 >> 9;
        int k = s * 32 + (L >> 4) * 8 + j;
        int i = L & 15;
        const float* Wsrc = (i < 8) ? Wi : Wp;
        const float* av = attn + (size_t)(i & 7) * 64;
        float v = 0.f;
#pragma unroll 8
        for (int d = 0; d < 64; ++d) v += av[d] * Wsrc[d * 128 + k];
        unsigned short h = f2bf(v);
        Phi[t2] = h;
        Plo[t2] = f2bf(v - bf2f(h));
    }
}

// ---------------------------------------------------------------------------
// Dense GEMM: Ybf[M x 128] = feat[M x 128] @ B, split-bf16 (3 MFMA per tile),
// plus P[M x 16] = feat @ Wcomb as a 9th col-tile. No LDS, no barriers, no
// cross-lane ops. P stored directly from accumulator (C/D layout). (= R11)
__global__ __launch_bounds__(256, 4) void k_dense(
    const float* __restrict__ feat, const unsigned short* __restrict__ Whi,
    const unsigned short* __restrict__ Wlo, const unsigned short* __restrict__ Phi,
    const unsigned short* __restrict__ Plo,
    const int* __restrict__ edge_dst, const int* __restrict__ mult,
    int* __restrict__ count, unsigned short* __restrict__ Ybf,
    float* __restrict__ P, int M, int E) {
    int t = threadIdx.x;

    // edge-hist prologue (grid covers E: 1563 * 256 = 400k > 300k)
    {
        int e = blockIdx.x * 256 + t;
        if (e < E) {
            int d = edge_dst[e];
            if (mult[d] > 0) atomicAdd(&count[d], 1);
        }
    }

    int L = t & 63;
    int wave = t >> 6;
    int m = L & 15, q = L >> 4;
    int R0 = blockIdx.x * 64 + wave * 16;

    int rowc = R0 + m; if (rowc > M - 1) rowc = M - 1;
    const float* arow = feat + (size_t)rowc * 128;

    // hoist ALL A loads (8 x float4 = full 512B row slice for this lane)
    float4 av0[4], av1[4];
#pragma unroll
    for (int s = 0; s < 4; ++s) {
        const float4* ap = (const float4*)(arow + s * 32 + q * 8);
        av0[s] = ap[0];
        av1[s] = ap[1];
    }
    // convert all A to split hi/lo bf16 upfront
    bf16x8 ahi[4], alo[4];
#pragma unroll
    for (int s = 0; s < 4; ++s) {
        float av[8] = {av0[s].x, av0[s].y, av0[s].z, av0[s].w,
                       av1[s].x, av1[s].y, av1[s].z, av1[s].w};
#pragma unroll
        for (int j = 0; j < 8; ++j) {
            unsigned short h = f2bf(av[j]);
            ahi[s][j] = (short)h;
            alo[s][j] = (short)f2bf(av[j] - bf2f(h));
        }
    }

    f32x4 acc[8];
#pragma unroll
    for (int c = 0; c < 8; ++c) acc[c] = (f32x4){0.f, 0.f, 0.f, 0.f};
    f32x4 accP = (f32x4){0.f, 0.f, 0.f, 0.f};

    const bf16x8* gh = (const bf16x8*)Whi;
    const bf16x8* gl = (const bf16x8*)Wlo;
    const bf16x8* ph = (const bf16x8*)Phi;
    const bf16x8* pl = (const bf16x8*)Plo;
#pragma unroll
    for (int s = 0; s < 4; ++s) {
#pragma unroll
        for (int c = 0; c < 8; ++c) {
            bf16x8 bh = gh[(s * 8 + c) * 64 + L];
            bf16x8 bl = gl[(s * 8 + c) * 64 + L];
            acc[c] = __builtin_amdgcn_mfma_f32_16x16x32_bf16(ahi[s], bh, acc[c], 0, 0, 0);
            acc[c] = __builtin_amdgcn_mfma_f32_16x16x32_bf16(ahi[s], bl, acc[c], 0, 0, 0);
            acc[c] = __builtin_amdgcn_mfma_f32_16x16x32_bf16(alo[s], bh, acc[c], 0, 0, 0);
        }
        {
            bf16x8 bh = ph[s * 64 + L];
            bf16x8 bl = pl[s * 64 + L];
            accP = __builtin_amdgcn_mfma_f32_16x16x32_bf16(ahi[s], bh, accP, 0, 0, 0);
            accP = __builtin_amdgcn_mfma_f32_16x16x32_bf16(ahi[s], bl, accP, 0, 0, 0);
            accP = __builtin_amdgcn_mfma_f32_16x16x32_bf16(alo[s], bh, accP, 0, 0, 0);
        }
    }

    // C/D layout: col = lane&15 (=m), row = (lane>>4)*4 + reg (=q*4+r)
#pragma unroll
    for (int c = 0; c < 8; ++c) {
#pragma unroll
        for (int r = 0; r < 4; ++r) {
            int row = R0 + q * 4 + r;
            if (row < M) Ybf[(size_t)row * 128 + c * 16 + m] = f2bf(acc[c][r]);
        }
    }
    // P store: col i = m, rows q*4+r
#pragma unroll
    for (int r = 0; r < 4; ++r) {
        int row = R0 + q * 4 + r;
        if (row < M) P[(size_t)row * 16 + m] = accP[r];
    }
}

// ---------------------------------------------------------------------------
// per-block exclusive scan of count + block partial sums
__global__ __launch_bounds__(256) void k_scan1(
    const int* __restrict__ count, int* __restrict__ excl, int* __restrict__ partials, int N) {
    __shared__ int lds[256];
    int t = threadIdx.x, i = blockIdx.x * 256 + t;
    int c = (i < N) ? count[i] : 0;
    lds[t] = c; __syncthreads();
    for (int o = 1; o < 256; o <<= 1) {
        int v = (t >= o) ? lds[t - o] : 0;
        __syncthreads(); lds[t] += v; __syncthreads();
    }
    if (i < N) excl[i] = lds[t] - c;
    if (t == 255) partials[blockIdx.x] = lds[255];
}

// merged scan2+scan3
__global__ __launch_bounds__(256) void k_scan23(
    const int* __restrict__ excl, const int* __restrict__ partials,
    int* __restrict__ offsets, int* __restrict__ cursor, int N) {
    __shared__ int sacc[256];
    int bid = blockIdx.x, t = threadIdx.x;
    int s = 0;
    for (int j = t; j < bid; j += 256) s += partials[j];
    sacc[t] = s; __syncthreads();
#pragma unroll
    for (int o = 128; o > 0; o >>= 1) {
        if (t < o) sacc[t] += sacc[t + o];
        __syncthreads();
    }
    int boff = sacc[0];
    int i = bid * 256 + t;
    if (i < N) {
        int o = excl[i] + boff;
        offsets[i] = o; cursor[i] = o;
    }
    if (t == 0 && bid == gridDim.x - 1) offsets[N] = boff + partials[bid];
}

// ---------------------------------------------------------------------------
// Fused scatter + logits + per-(node,head) max (float-ordered atomicMax).
// 8 lanes per edge (h = lane&7).
__global__ __launch_bounds__(256) void k_scatter_logits(
    const int* __restrict__ edge_dst, const int* __restrict__ mult,
    int* __restrict__ cursor, const int* __restrict__ mp,
    const float* __restrict__ P, const float* __restrict__ Wth,
    float* __restrict__ logits, int4* __restrict__ mpc,
    unsigned* __restrict__ mxkey, int E) {
    int e = blockIdx.x * 32 + (threadIdx.x >> 3);
    if (e >= E) return;
    int h = threadIdx.x & 7;
    int d = edge_dst[e];
    if (mult[d] == 0) return;
    int pos = 0;
    if (h == 0) pos = atomicAdd(&cursor[d], 1);
    int gbase = threadIdx.x & ~7;
    pos = __shfl(pos, gbase);
    int4 rows = *(const int4*)(mp + (size_t)e * 4);
    float s = P[(size_t)rows.x * 16 + h] + P[(size_t)rows.w * 16 + h]
            + P[(size_t)rows.y * 16 + 8 + h] + P[(size_t)rows.z * 16 + 8 + h];
    float l = 0.f;
#pragma unroll
    for (int j = 0; j < 8; ++j) {
        float sj = __shfl(s, gbase + j);
        l += Wth[h * 8 + j] * sj;
    }
    l = l > 0.f ? l : 0.01f * l;
    logits[(size_t)pos * 8 + h] = l;
    atomicMax(&mxkey[(size_t)d * 8 + h], fenc(l));
    if (h == 0) mpc[pos] = rows;
}

// ---------------------------------------------------------------------------
// Per flagged node: plain softmax (max precomputed in mxkey) + aggregation.
// Block = 2 nodes x 2 waves; waves take alternating edges, partials combined
// via LDS -> per-node serial gather chain halves. No early returns (barrier).
__global__ __launch_bounds__(256) void k_node_agg(
    const unsigned short* __restrict__ Ybf, const float* __restrict__ logits,
    const int4* __restrict__ mpc, const int* __restrict__ offsets,
    const int* __restrict__ mult, const unsigned* __restrict__ mxkey,
    const float* __restrict__ Wg,
    unsigned short* __restrict__ nftb, float* __restrict__ gate_part, int N) {
    __shared__ float sacc[2][8][64];
    __shared__ float sden[2][8];
    int t = threadIdx.x;
    int pair = t >> 7;          // node within block (0,1)
    int wp   = (t >> 6) & 1;    // wave within pair
    int lane = t & 63;
    int n = blockIdx.x * 2 + pair;

    int m = 0, beg = 0, end = 0;
    bool active = false;
    if (n < N) { m = mult[n]; active = (m > 0); }

    float mx[8], den[8], acc[8];
#pragma unroll
    for (int h = 0; h < 8; ++h) { mx[h] = 0.f; den[h] = 0.f; acc[h] = 0.f; }
    if (active) {
        beg = offsets[n]; end = offsets[n + 1];
#pragma unroll
        for (int h = 0; h < 8; ++h) mx[h] = fdec(mxkey[(size_t)n * 8 + h]);
    }

    for (int j = beg + wp; j < end; j += 2) {
        const float4* lp = (const float4*)(logits + (size_t)j * 8);
        float4 l0 = lp[0], l1 = lp[1];
        int4 rows = mpc[j];
        float ed = bf2f(Ybf[(size_t)rows.x * 128 + lane])
                 + bf2f(Ybf[(size_t)rows.w * 128 + lane])
                 + bf2f(Ybf[(size_t)rows.y * 128 + 64 + lane])
                 + bf2f(Ybf[(size_t)rows.z * 128 + 64 + lane]);
        float w0 = __expf(l0.x - mx[0]), w1 = __expf(l0.y - mx[1]);
        float w2 = __expf(l0.z - mx[2]), w3 = __expf(l0.w - mx[3]);
        float w4 = __expf(l1.x - mx[4]), w5 = __expf(l1.y - mx[5]);
        float w6 = __expf(l1.z - mx[6]), w7 = __expf(l1.w - mx[7]);
        den[0] += w0; den[1] += w1; den[2] += w2; den[3] += w3;
        den[4] += w4; den[5] += w5; den[6] += w6; den[7] += w7;
        acc[0] += w0 * ed; acc[1] += w1 * ed; acc[2] += w2 * ed; acc[3] += w3 * ed;
        acc[4] += w4 * ed; acc[5] += w5 * ed; acc[6] += w6 * ed; acc[7] += w7 * ed;
    }

    // wave 1 publishes partials (zeros if inactive -- harmless)
    if (wp == 1) {
#pragma unroll
        for (int h = 0; h < 8; ++h) sacc[pair][h][lane] = acc[h];
        // den is lane-invariant; extract den[lane] without dynamic indexing
        float dv = 0.f;
#pragma unroll
        for (int h = 0; h < 8; ++h) dv = (lane == h) ? den[h] : dv;
        if (lane < 8) sden[pair][lane] = dv;
    }
    __syncthreads();

    if (wp == 0 && active) {
#pragma unroll
        for (int h = 0; h < 8; ++h) {
            acc[h] += sacc[pair][h][lane];
            den[h] += sden[pair][h];
            float r = (end > beg) ? 1.f / den[h] : 0.f;
            acc[h] *= r;
        }

        unsigned short* base = nftb + (size_t)n * 512;
#pragma unroll
        for (int h = 0; h < 8; ++h) base[h * 64 + lane] = f2bf(acc[h]);

        float wg = Wg[lane];
        float myg = 0.f;
#pragma unroll
        for (int h = 0; h < 8; ++h) {
            float p = acc[h] * wg;
#pragma unroll
            for (int o = 32; o > 0; o >>= 1) p += __shfl_xor(p, o);
            if (lane == h) myg = p;
        }
        if (lane < 8)
            atomicAdd(&gate_part[(blockIdx.x & 255) * 8 + lane], (float)m * myg);
    }
}

// ---------------------------------------------------------------------------
// Output with folded gate reduction: each block redundantly reduces the 256
// gate_part slots (8KB, L2-resident), then does the gated gather-store.
__global__ __launch_bounds__(256) void k_output(
    const unsigned short* __restrict__ nftb, const int* __restrict__ batch_nodes,
    const float* __restrict__ gate_part, const float* __restrict__ b_gate,
    float* __restrict__ out, int B) {
    __shared__ float lds[256];
    __shared__ float sg[8];
    int t = threadIdx.x;
    {
        int h = t & 7, g = t >> 3;
        float s = 0.f;
        for (int b = g; b < 256; b += 32) s += gate_part[b * 8 + h];
        lds[t] = s; __syncthreads();
        if (t < 8) {
            float tot = 0.f;
            for (int gg = 0; gg < 32; ++gg) tot += lds[gg * 8 + t];
            sg[t] = tot / (float)B + b_gate[0];
        }
        __syncthreads();
    }
    int idx = blockIdx.x * 256 + t;
    int total = B * 64;
    if (idx >= total) return;
    int b = idx >> 6;
    int r = idx & 63;
    int h = r >> 3;
    int n = batch_nodes[b];
    u16x8 v = *(const u16x8*)(nftb + (size_t)n * 512 + r * 8);
    float g = sg[h];
    f32x4 o0, o1;
    o0[0] = bf2f(v[0]) * g; o0[1] = bf2f(v[1]) * g;
    o0[2] = bf2f(v[2]) * g; o0[3] = bf2f(v[3]) * g;
    o1[0] = bf2f(v[4]) * g; o1[1] = bf2f(v[5]) * g;
    o1[2] = bf2f(v[6]) * g; o1[3] = bf2f(v[7]) * g;
    f32x4* op = (f32x4*)(out + (size_t)idx * 8);
    __builtin_nontemporal_store(o0, op);
    __builtin_nontemporal_store(o1, op + 1);
}

// ---------------------------------------------------------------------------
extern "C" void kernel_launch(void* const* d_in, const int* in_sizes, int n_in,
                              void* d_out, int out_size, void* d_ws, size_t ws_size,
                              hipStream_t stream) {
    const int*   batch_nodes = (const int*)d_in[0];
    const int*   mp          = (const int*)d_in[1];
    const int*   edge_dst    = (const int*)d_in[2];
    const float* feat        = (const float*)d_in[3];
    const float* W_i         = (const float*)d_in[4];
    const float* W_p         = (const float*)d_in[5];
    const float* attn        = (const float*)d_in[6];
    const float* W_th        = (const float*)d_in[7];
    const float* W_gate      = (const float*)d_in[8];
    const float* b_gate      = (const float*)d_in[9];
    float* out = (float*)d_out;

    const int B = in_sizes[0];
    const int E = in_sizes[2];
    const int N = in_sizes[3] / 128;
    const int nb_scan = (N + 255) / 256;

    char* w = (char*)d_ws;
    auto alloc = [&](size_t bytes) -> void* {
        void* p = (void*)w;
        w += (bytes + 255) & ~(size_t)255;
        return p;
    };
    unsigned short* Whi = (unsigned short*)alloc(16384 * 2);
    unsigned short* Wlo = (unsigned short*)alloc(16384 * 2);
    unsigned short* Phi = (unsigned short*)alloc(2048 * 2);
    unsigned short* Plo = (unsigned short*)alloc(2048 * 2);
    unsigned short* Ybf = (unsigned short*)alloc((size_t)N * 128 * 2);   // 25.6 MB
    float* P            = (float*)alloc((size_t)N * 16 * 4);             // 6.4 MB
    float* logits       = (float*)alloc((size_t)E * 8 * 4);              // 9.6 MB
    int4*  mpc          = (int4*)alloc((size_t)E * 16);                  // 4.8 MB
    // contiguous zero region: mult | count | gate_part | mxkey (single memset)
    size_t zero_bytes   = (size_t)N * 4 + (size_t)N * 4 + 256 * 8 * 4
                        + (size_t)N * 8 * 4;
    int*   mult         = (int*)alloc(zero_bytes);
    int*   count        = mult + N;
    float* gate_part    = (float*)(count + N);
    unsigned* mxkey     = (unsigned*)(gate_part + 256 * 8);
    int*   excl         = (int*)alloc((size_t)N * 4);
    int*   offsets      = (int*)alloc((size_t)(N + 1) * 4);
    int*   cursor       = (int*)alloc((size_t)N * 4);
    int*   partials     = (int*)alloc(512 * 4);
    unsigned short* nftb = (unsigned short*)alloc((size_t)N * 512 * 2);  // 102.4 MB

    hipMemsetAsync(mult, 0, zero_bytes, stream);

    int prep_work = (B > 16384 + 2048) ? B : 16384 + 2048;
    k_prep<<<(prep_work + 255) / 256, 256, 0, stream>>>(W_i, W_p, attn,
                                                        Whi, Wlo, Phi, Plo,
                                                        batch_nodes, mult, B);
    k_dense<<<(N + 63) / 64, 256, 0, stream>>>(feat, Whi, Wlo, Phi, Plo,
                                               edge_dst, mult, count, Ybf, P, N, E);
    k_scan1<<<nb_scan, 256, 0, stream>>>(count, excl, partials, N);
    k_scan23<<<nb_scan, 256, 0, stream>>>(excl, partials, offsets, cursor, N);
    k_scatter_logits<<<(E + 31) / 32, 256, 0, stream>>>(edge_dst, mult, cursor,
                                                        mp, P, W_th, logits, mpc,
                                                        mxkey, E);
    k_node_agg<<<(N + 1) / 2, 256, 0, stream>>>(Ybf, logits, mpc, offsets, mult,
                                                mxkey, W_gate, nftb, gate_part, N);
    k_output<<<(B * 64 + 255) / 256, 256, 0, stream>>>(nftb, batch_nodes,
                                                       gate_part, b_gate, out, B);
}

// Round 13
// 303.437 us; speedup vs baseline: 1.0755x; 1.0332x over previous
//
#include <hip/hip_runtime.h>
#include <cstdint>
#include <cstddef>

// N=100000, E=300000, B=50000, L=4, D_EMB=128, D_HID=64, H=8. fp32 in/out.
// R15: node_agg gate-reduce amortization. R14 evidence: per-node FIXED
// overhead dominates (~48 shfl DS-ops/node for the gate dot vs ~3 edges of
// work). Now: single wave per node (R11 body) but GRID-STRIDE over ~12
// nodes/wave; per node gate partial = 8 reg fma; the 48-shuffle reduce +
// atomicAdd runs ONCE per wave. gatefinal stays folded into k_output
// (R14's validated piece; gate_part = 256 slots). Rest identical to R11.
// Dispatches: 8 (memset, prep, dense(+hist), scan1, scan23, scatter_logits,
//                node_agg, output(+gate)).

typedef __attribute__((ext_vector_type(8))) short bf16x8;
typedef __attribute__((ext_vector_type(4))) float f32x4;
typedef __attribute__((ext_vector_type(8))) unsigned short u16x8;

__device__ __forceinline__ unsigned short f2bf(float f) {
    unsigned u = __float_as_uint(f);
    unsigned r = u + 0x7fffu + ((u >> 16) & 1u);
    return (unsigned short)(r >> 16);
}
__device__ __forceinline__ float bf2f(unsigned short h) {
    return __uint_as_float((unsigned)h << 16);
}
// monotonic float<->unsigned order-preserving encode (for atomicMax)
__device__ __forceinline__ unsigned fenc(float f) {
    unsigned u = __float_as_uint(f);
    return (u & 0x80000000u) ? ~u : (u | 0x80000000u);
}
__device__ __forceinline__ float fdec(unsigned k) {
    unsigned u = (k & 0x80000000u) ? (k & 0x7fffffffu) : ~k;
    return __uint_as_float(u);
}

// ---------------------------------------------------------------------------
// Pack B = [Wi;Wp].T (K=128 x N=128) into MFMA B-frag order, split hi/lo bf16.
// Also pack Wcomb[128x16] (col i<8: Wi^T@attn_i; col 8+i: Wp^T@attn_i) as a
// single extra B-frag tile (Phi/Plo). Fused: batch-node multiplicity hist.
__global__ __launch_bounds__(256) void k_prep(
    const float* __restrict__ Wi, const float* __restrict__ Wp,
    const float* __restrict__ attn,
    unsigned short* __restrict__ Whi, unsigned short* __restrict__ Wlo,
    unsigned short* __restrict__ Phi, unsigned short* __restrict__ Plo,
    const int* __restrict__ batch_nodes, int* __restrict__ mult, int B) {
    int t = blockIdx.x * 256 + threadIdx.x;
    if (t < B) atomicAdd(&mult[batch_nodes[t]], 1);
    if (t < 16384) {
        int j = t & 7, L = (t >> 3) & 63, c = (t >> 9) & 7, s = t >> 12;
        int k = s * 32 + (L >> 4) * 8 + j;
        int n = c * 16 + (L & 15);
        float v = (n < 64) ? Wi[n * 128 + k] : Wp[(n - 64) * 128 + k];
        unsigned short h = f2bf(v);
        Whi[t] = h;
        Wlo[t] = f2bf(v - bf2f(h));
    } else if (t < 16384 + 2048) {
        int t2 = t - 16384;
        int j = t2 & 7, L = (t2 >> 3) & 63, s = t2 >> 9;
        int k = s * 32 + (L >> 4) * 8 + j;
        int i = L & 15;
        const float* Wsrc = (i < 8) ? Wi : Wp;
        const float* av = attn + (size_t)(i & 7) * 64;
        float v = 0.f;
#pragma unroll 8
        for (int d = 0; d < 64; ++d) v += av[d] * Wsrc[d * 128 + k];
        unsigned short h = f2bf(v);
        Phi[t2] = h;
        Plo[t2] = f2bf(v - bf2f(h));
    }
}

// ---------------------------------------------------------------------------
// Dense GEMM: Ybf[M x 128] = feat[M x 128] @ B, split-bf16 (3 MFMA per tile),
// plus P[M x 16] = feat @ Wcomb as a 9th col-tile. No LDS, no barriers, no
// cross-lane ops. P stored directly from accumulator (C/D layout). (= R11)
__global__ __launch_bounds__(256, 4) void k_dense(
    const float* __restrict__ feat, const unsigned short* __restrict__ Whi,
    const unsigned short* __restrict__ Wlo, const unsigned short* __restrict__ Phi,
    const unsigned short* __restrict__ Plo,
    const int* __restrict__ edge_dst, const int* __restrict__ mult,
    int* __restrict__ count, unsigned short* __restrict__ Ybf,
    float* __restrict__ P, int M, int E) {
    int t = threadIdx.x;

    // edge-hist prologue (grid covers E: 1563 * 256 = 400k > 300k)
    {
        int e = blockIdx.x * 256 + t;
        if (e < E) {
            int d = edge_dst[e];
            if (mult[d] > 0) atomicAdd(&count[d], 1);
        }
    }

    int L = t & 63;
    int wave = t >> 6;
    int m = L & 15, q = L >> 4;
    int R0 = blockIdx.x * 64 + wave * 16;

    int rowc = R0 + m; if (rowc > M - 1) rowc = M - 1;
    const float* arow = feat + (size_t)rowc * 128;

    // hoist ALL A loads (8 x float4 = full 512B row slice for this lane)
    float4 av0[4], av1[4];
#pragma unroll
    for (int s = 0; s < 4; ++s) {
        const float4* ap = (const float4*)(arow + s * 32 + q * 8);
        av0[s] = ap[0];
        av1[s] = ap[1];
    }
    // convert all A to split hi/lo bf16 upfront
    bf16x8 ahi[4], alo[4];
#pragma unroll
    for (int s = 0; s < 4; ++s) {
        float av[8] = {av0[s].x, av0[s].y, av0[s].z, av0[s].w,
                       av1[s].x, av1[s].y, av1[s].z, av1[s].w};
#pragma unroll
        for (int j = 0; j < 8; ++j) {
            unsigned short h = f2bf(av[j]);
            ahi[s][j] = (short)h;
            alo[s][j] = (short)f2bf(av[j] - bf2f(h));
        }
    }

    f32x4 acc[8];
#pragma unroll
    for (int c = 0; c < 8; ++c) acc[c] = (f32x4){0.f, 0.f, 0.f, 0.f};
    f32x4 accP = (f32x4){0.f, 0.f, 0.f, 0.f};

    const bf16x8* gh = (const bf16x8*)Whi;
    const bf16x8* gl = (const bf16x8*)Wlo;
    const bf16x8* ph = (const bf16x8*)Phi;
    const bf16x8* pl = (const bf16x8*)Plo;
#pragma unroll
    for (int s = 0; s < 4; ++s) {
#pragma unroll
        for (int c = 0; c < 8; ++c) {
            bf16x8 bh = gh[(s * 8 + c) * 64 + L];
            bf16x8 bl = gl[(s * 8 + c) * 64 + L];
            acc[c] = __builtin_amdgcn_mfma_f32_16x16x32_bf16(ahi[s], bh, acc[c], 0, 0, 0);
            acc[c] = __builtin_amdgcn_mfma_f32_16x16x32_bf16(ahi[s], bl, acc[c], 0, 0, 0);
            acc[c] = __builtin_amdgcn_mfma_f32_16x16x32_bf16(alo[s], bh, acc[c], 0, 0, 0);
        }
        {
            bf16x8 bh = ph[s * 64 + L];
            bf16x8 bl = pl[s * 64 + L];
            accP = __builtin_amdgcn_mfma_f32_16x16x32_bf16(ahi[s], bh, accP, 0, 0, 0);
            accP = __builtin_amdgcn_mfma_f32_16x16x32_bf16(ahi[s], bl, accP, 0, 0, 0);
            accP = __builtin_amdgcn_mfma_f32_16x16x32_bf16(alo[s], bh, accP, 0, 0, 0);
        }
    }

    // C/D layout: col = lane&15 (=m), row = (lane>>4)*4 + reg (=q*4+r)
#pragma unroll
    for (int c = 0; c < 8; ++c) {
#pragma unroll
        for (int r = 0; r < 4; ++r) {
            int row = R0 + q * 4 + r;
            if (row < M) Ybf[(size_t)row * 128 + c * 16 + m] = f2bf(acc[c][r]);
        }
    }
    // P store: col i = m, rows q*4+r
#pragma unroll
    for (int r = 0; r < 4; ++r) {
        int row = R0 + q * 4 + r;
        if (row < M) P[(size_t)row * 16 + m] = accP[r];
    }
}

// ---------------------------------------------------------------------------
// per-block exclusive scan of count + block partial sums
__global__ __launch_bounds__(256) void k_scan1(
    const int* __restrict__ count, int* __restrict__ excl, int* __restrict__ partials, int N) {
    __shared__ int lds[256];
    int t = threadIdx.x, i = blockIdx.x * 256 + t;
    int c = (i < N) ? count[i] : 0;
    lds[t] = c; __syncthreads();
    for (int o = 1; o < 256; o <<= 1) {
        int v = (t >= o) ? lds[t - o] : 0;
        __syncthreads(); lds[t] += v; __syncthreads();
    }
    if (i < N) excl[i] = lds[t] - c;
    if (t == 255) partials[blockIdx.x] = lds[255];
}

// merged scan2+scan3
__global__ __launch_bounds__(256) void k_scan23(
    const int* __restrict__ excl, const int* __restrict__ partials,
    int* __restrict__ offsets, int* __restrict__ cursor, int N) {
    __shared__ int sacc[256];
    int bid = blockIdx.x, t = threadIdx.x;
    int s = 0;
    for (int j = t; j < bid; j += 256) s += partials[j];
    sacc[t] = s; __syncthreads();
#pragma unroll
    for (int o = 128; o > 0; o >>= 1) {
        if (t < o) sacc[t] += sacc[t + o];
        __syncthreads();
    }
    int boff = sacc[0];
    int i = bid * 256 + t;
    if (i < N) {
        int o = excl[i] + boff;
        offsets[i] = o; cursor[i] = o;
    }
    if (t == 0 && bid == gridDim.x - 1) offsets[N] = boff + partials[bid];
}

// ---------------------------------------------------------------------------
// Fused scatter + logits + per-(node,head) max (float-ordered atomicMax).
// 8 lanes per edge (h = lane&7).
__global__ __launch_bounds__(256) void k_scatter_logits(
    const int* __restrict__ edge_dst, const int* __restrict__ mult,
    int* __restrict__ cursor, const int* __restrict__ mp,
    const float* __restrict__ P, const float* __restrict__ Wth,
    float* __restrict__ logits, int4* __restrict__ mpc,
    unsigned* __restrict__ mxkey, int E) {
    int e = blockIdx.x * 32 + (threadIdx.x >> 3);
    if (e >= E) return;
    int h = threadIdx.x & 7;
    int d = edge_dst[e];
    if (mult[d] == 0) return;
    int pos = 0;
    if (h == 0) pos = atomicAdd(&cursor[d], 1);
    int gbase = threadIdx.x & ~7;
    pos = __shfl(pos, gbase);
    int4 rows = *(const int4*)(mp + (size_t)e * 4);
    float s = P[(size_t)rows.x * 16 + h] + P[(size_t)rows.w * 16 + h]
            + P[(size_t)rows.y * 16 + 8 + h] + P[(size_t)rows.z * 16 + 8 + h];
    float l = 0.f;
#pragma unroll
    for (int j = 0; j < 8; ++j) {
        float sj = __shfl(s, gbase + j);
        l += Wth[h * 8 + j] * sj;
    }
    l = l > 0.f ? l : 0.01f * l;
    logits[(size_t)pos * 8 + h] = l;
    atomicMax(&mxkey[(size_t)d * 8 + h], fenc(l));
    if (h == 0) mpc[pos] = rows;
}

// ---------------------------------------------------------------------------
// Grid-stride: one wave per node, ~12 nodes per wave. Plain softmax (max in
// mxkey) + aggregation. Gate partials accumulate in REGISTERS across nodes
// (8 fma/node); the 48-shuffle reduce + atomicAdd runs once per wave.
__global__ __launch_bounds__(256) void k_node_agg(
    const unsigned short* __restrict__ Ybf, const float* __restrict__ logits,
    const int4* __restrict__ mpc, const int* __restrict__ offsets,
    const int* __restrict__ mult, const unsigned* __restrict__ mxkey,
    const float* __restrict__ Wg,
    unsigned short* __restrict__ nftb, float* __restrict__ gate_part, int N) {
    int lane = threadIdx.x & 63;
    int gwave = blockIdx.x * 4 + (threadIdx.x >> 6);
    int nwaves = gridDim.x * 4;
    float wg = Wg[lane];

    float gp[8];
#pragma unroll
    for (int h = 0; h < 8; ++h) gp[h] = 0.f;

    for (int n = gwave; n < N; n += nwaves) {
        int m = mult[n];
        if (m == 0) continue;
        int beg = offsets[n], end = offsets[n + 1];

        float mx[8], den[8], acc[8];
#pragma unroll
        for (int h = 0; h < 8; ++h) {
            mx[h] = fdec(mxkey[(size_t)n * 8 + h]);
            den[h] = 0.f; acc[h] = 0.f;
        }

        for (int j = beg; j < end; ++j) {
            const float4* lp = (const float4*)(logits + (size_t)j * 8);
            float4 l0 = lp[0], l1 = lp[1];
            int4 rows = mpc[j];
            float ed = bf2f(Ybf[(size_t)rows.x * 128 + lane])
                     + bf2f(Ybf[(size_t)rows.w * 128 + lane])
                     + bf2f(Ybf[(size_t)rows.y * 128 + 64 + lane])
                     + bf2f(Ybf[(size_t)rows.z * 128 + 64 + lane]);
            float w0 = __expf(l0.x - mx[0]), w1 = __expf(l0.y - mx[1]);
            float w2 = __expf(l0.z - mx[2]), w3 = __expf(l0.w - mx[3]);
            float w4 = __expf(l1.x - mx[4]), w5 = __expf(l1.y - mx[5]);
            float w6 = __expf(l1.z - mx[6]), w7 = __expf(l1.w - mx[7]);
            den[0] += w0; den[1] += w1; den[2] += w2; den[3] += w3;
            den[4] += w4; den[5] += w5; den[6] += w6; den[7] += w7;
            acc[0] += w0 * ed; acc[1] += w1 * ed; acc[2] += w2 * ed; acc[3] += w3 * ed;
            acc[4] += w4 * ed; acc[5] += w5 * ed; acc[6] += w6 * ed; acc[7] += w7 * ed;
        }

#pragma unroll
        for (int h = 0; h < 8; ++h) {
            float r = (end > beg) ? 1.f / den[h] : 0.f;
            acc[h] *= r;
        }

        unsigned short* base = nftb + (size_t)n * 512;
#pragma unroll
        for (int h = 0; h < 8; ++h) base[h * 64 + lane] = f2bf(acc[h]);

        // register gate partial: no cross-lane ops per node
#pragma unroll
        for (int h = 0; h < 8; ++h) gp[h] += (float)m * acc[h];
    }

    // once per wave: reduce gate partials over lanes
    float myg = 0.f;
#pragma unroll
    for (int h = 0; h < 8; ++h) {
        float p = gp[h] * wg;
#pragma unroll
        for (int o = 32; o > 0; o >>= 1) p += __shfl_xor(p, o);
        if (lane == h) myg = p;
    }
    if (lane < 8)
        atomicAdd(&gate_part[(blockIdx.x & 255) * 8 + lane], myg);
}

// ---------------------------------------------------------------------------
// Output with folded gate reduction: each block redundantly reduces the 256
// gate_part slots (8KB, L2-resident), then does the gated gather-store.
__global__ __launch_bounds__(256) void k_output(
    const unsigned short* __restrict__ nftb, const int* __restrict__ batch_nodes,
    const float* __restrict__ gate_part, const float* __restrict__ b_gate,
    float* __restrict__ out, int B) {
    __shared__ float lds[256];
    __shared__ float sg[8];
    int t = threadIdx.x;
    {
        int h = t & 7, g = t >> 3;
        float s = 0.f;
        for (int b = g; b < 256; b += 32) s += gate_part[b * 8 + h];
        lds[t] = s; __syncthreads();
        if (t < 8) {
            float tot = 0.f;
            for (int gg = 0; gg < 32; ++gg) tot += lds[gg * 8 + t];
            sg[t] = tot / (float)B + b_gate[0];
        }
        __syncthreads();
    }
    int idx = blockIdx.x * 256 + t;
    int total = B * 64;
    if (idx >= total) return;
    int b = idx >> 6;
    int r = idx & 63;
    int h = r >> 3;
    int n = batch_nodes[b];
    u16x8 v = *(const u16x8*)(nftb + (size_t)n * 512 + r * 8);
    float g = sg[h];
    f32x4 o0, o1;
    o0[0] = bf2f(v[0]) * g; o0[1] = bf2f(v[1]) * g;
    o0[2] = bf2f(v[2]) * g; o0[3] = bf2f(v[3]) * g;
    o1[0] = bf2f(v[4]) * g; o1[1] = bf2f(v[5]) * g;
    o1[2] = bf2f(v[6]) * g; o1[3] = bf2f(v[7]) * g;
    f32x4* op = (f32x4*)(out + (size_t)idx * 8);
    __builtin_nontemporal_store(o0, op);
    __builtin_nontemporal_store(o1, op + 1);
}

// ---------------------------------------------------------------------------
extern "C" void kernel_launch(void* const* d_in, const int* in_sizes, int n_in,
                              void* d_out, int out_size, void* d_ws, size_t ws_size,
                              hipStream_t stream) {
    const int*   batch_nodes = (const int*)d_in[0];
    const int*   mp          = (const int*)d_in[1];
    const int*   edge_dst    = (const int*)d_in[2];
    const float* feat        = (const float*)d_in[3];
    const float* W_i         = (const float*)d_in[4];
    const float* W_p         = (const float*)d_in[5];
    const float* attn        = (const float*)d_in[6];
    const float* W_th        = (const float*)d_in[7];
    const float* W_gate      = (const float*)d_in[8];
    const float* b_gate      = (const float*)d_in[9];
    float* out = (float*)d_out;

    const int B = in_sizes[0];
    const int E = in_sizes[2];
    const int N = in_sizes[3] / 128;
    const int nb_scan = (N + 255) / 256;

    char* w = (char*)d_ws;
    auto alloc = [&](size_t bytes) -> void* {
        void* p = (void*)w;
        w += (bytes + 255) & ~(size_t)255;
        return p;
    };
    unsigned short* Whi = (unsigned short*)alloc(16384 * 2);
    unsigned short* Wlo = (unsigned short*)alloc(16384 * 2);
    unsigned short* Phi = (unsigned short*)alloc(2048 * 2);
    unsigned short* Plo = (unsigned short*)alloc(2048 * 2);
    unsigned short* Ybf = (unsigned short*)alloc((size_t)N * 128 * 2);   // 25.6 MB
    float* P            = (float*)alloc((size_t)N * 16 * 4);             // 6.4 MB
    float* logits       = (float*)alloc((size_t)E * 8 * 4);              // 9.6 MB
    int4*  mpc          = (int4*)alloc((size_t)E * 16);                  // 4.8 MB
    // contiguous zero region: mult | count | gate_part | mxkey (single memset)
    size_t zero_bytes   = (size_t)N * 4 + (size_t)N * 4 + 256 * 8 * 4
                        + (size_t)N * 8 * 4;
    int*   mult         = (int*)alloc(zero_bytes);
    int*   count        = mult + N;
    float* gate_part    = (float*)(count + N);
    unsigned* mxkey     = (unsigned*)(gate_part + 256 * 8);
    int*   excl         = (int*)alloc((size_t)N * 4);
    int*   offsets      = (int*)alloc((size_t)(N + 1) * 4);
    int*   cursor       = (int*)alloc((size_t)N * 4);
    int*   partials     = (int*)alloc(512 * 4);
    unsigned short* nftb = (unsigned short*)alloc((size_t)N * 512 * 2);  // 102.4 MB

    hipMemsetAsync(mult, 0, zero_bytes, stream);

    int prep_work = (B > 16384 + 2048) ? B : 16384 + 2048;
    k_prep<<<(prep_work + 255) / 256, 256, 0, stream>>>(W_i, W_p, attn,
                                                        Whi, Wlo, Phi, Plo,
                                                        batch_nodes, mult, B);
    k_dense<<<(N + 63) / 64, 256, 0, stream>>>(feat, Whi, Wlo, Phi, Plo,
                                               edge_dst, mult, count, Ybf, P, N, E);
    k_scan1<<<nb_scan, 256, 0, stream>>>(count, excl, partials, N);
    k_scan23<<<nb_scan, 256, 0, stream>>>(excl, partials, offsets, cursor, N);
    k_scatter_logits<<<(E + 31) / 32, 256, 0, stream>>>(edge_dst, mult, cursor,
                                                        mp, P, W_th, logits, mpc,
                                                        mxkey, E);
    k_node_agg<<<2048, 256, 0, stream>>>(Ybf, logits, mpc, offsets, mult,
                                         mxkey, W_gate, nftb, gate_part, N);
    k_output<<<(B * 64 + 255) / 256, 256, 0, stream>>>(nftb, batch_nodes,
                                                       gate_part, b_gate, out, B);
}